// Round 9
// baseline (114.119 us; speedup 1.0000x reference)
//
#include <hip/hip_runtime.h>

#define TT 200
#define FF 32
#define HH 50
#define PITCH 68   // f32 pitch of h LDS rows

typedef __attribute__((ext_vector_type(8))) short short8;   // 8 bf16 = 4 VGPR
typedef __attribute__((ext_vector_type(4))) float f32x4;

__device__ __forceinline__ unsigned short f2bf_rne(float f) {
    unsigned u = __float_as_uint(f);
    unsigned r = u + 0x7fffu + ((u >> 16) & 1u);
    return (unsigned short)(r >> 16);
}
// tanh(x) = 1 - 2/(e^{2x}+1)
__device__ __forceinline__ float fast_tanh(float x) {
    float e = __expf(2.0f * x);
    return fmaf(-2.0f, __builtin_amdgcn_rcpf(e + 1.0f), 1.0f);
}
__device__ __forceinline__ f32x4 mfma16(short8 a, short8 b, f32x4 c) {
    return __builtin_amdgcn_mfma_f32_16x16x32_bf16(a, b, c, 0, 0, 0);
}

// Split fp32 column-slice of M[kdim x 50] into bf16 hi/lo B-frags.
// Layout (validated r4-r8): lane(r,g) elem e -> B[k=kbase+8g+e][col=c].
__device__ __forceinline__ void build_bfrag(const float* __restrict__ M, int kbase,
                                            int kmax, int c, bool cv, int g,
                                            short8& hi, short8& lo) {
    typedef __attribute__((ext_vector_type(4))) unsigned int uint32x4;
    unsigned ph[4], pl[4];
#pragma unroll
    for (int p = 0; p < 4; ++p) {
        const int k0 = kbase + 8 * g + 2 * p, k1 = k0 + 1;
        float v0 = (cv && k0 < kmax) ? M[k0 * HH + c] : 0.0f;
        float v1 = (cv && k1 < kmax) ? M[k1 * HH + c] : 0.0f;
        unsigned short h0 = f2bf_rne(v0), h1 = f2bf_rne(v1);
        ph[p] = ((unsigned)h1 << 16) | h0;
        float r0 = v0 - __uint_as_float((unsigned)h0 << 16);
        float r1 = v1 - __uint_as_float((unsigned)h1 << 16);
        unsigned short l0 = f2bf_rne(r0), l1 = f2bf_rne(r1);
        pl[p] = ((unsigned)l1 << 16) | l0;
    }
    uint32x4 h4 = {ph[0], ph[1], ph[2], ph[3]};
    uint32x4 l4 = {pl[0], pl[1], pl[2], pl[3]};
    hi = __builtin_bit_cast(short8, h4);
    lo = __builtin_bit_cast(short8, l4);
}

// Truncation-split 8 fp32 -> bf16 hi/lo A-frags (hi=top16, lo=residual).
__device__ __forceinline__ void split8(float4 a, float4 b, short8& hi, short8& lo) {
    typedef __attribute__((ext_vector_type(4))) unsigned int uint32x4;
    float v[8] = {a.x, a.y, a.z, a.w, b.x, b.y, b.z, b.w};
    unsigned ph[4], pl[4];
#pragma unroll
    for (int p = 0; p < 4; ++p) {
        unsigned u0 = __float_as_uint(v[2 * p]);
        unsigned u1 = __float_as_uint(v[2 * p + 1]);
        ph[p] = __builtin_amdgcn_perm(u1, u0, 0x07060302u);
        float r0 = v[2 * p]     - __uint_as_float(u0 & 0xffff0000u);
        float r1 = v[2 * p + 1] - __uint_as_float(u1 & 0xffff0000u);
        pl[p] = __builtin_amdgcn_perm(__float_as_uint(r1), __float_as_uint(r0), 0x07060302u);
    }
    uint32x4 h4 = {ph[0], ph[1], ph[2], ph[3]};
    uint32x4 l4 = {pl[0], pl[1], pl[2], pl[3]};
    hi = __builtin_bit_cast(short8, h4);
    lo = __builtin_bit_cast(short8, l4);
}

// Block = 4 waves = ONE 8-row group, one 16-col N-tile per wave.
// 512 blocks -> 2 blocks/CU with INDEPENDENT barriers: the co-resident
// block drifts out of phase and fills this block's post-barrier stalls
// (r8 post-mortem: same-block waves are phase-LOCKED by the shared
// barrier, so 50% of the wall was coincident dependency stall).
// MFMA rows 8..15 are duplicates of 0..7 (reads clamped r&7) — we spend
// the idle half of the machine to buy phase diversity.
__global__
__attribute__((amdgpu_flat_work_group_size(256, 256)))
__attribute__((amdgpu_waves_per_eu(2)))
void rnn_mfma(const float* __restrict__ x, const float* __restrict__ W,
              const float* __restrict__ U, const float* __restrict__ b,
              const float* __restrict__ Wd, const float* __restrict__ bd,
              float* __restrict__ out)
{
    __shared__ float hbuf[2][8][PITCH];   // 8 real rows; junk cols write 0
    __shared__ float headbuf[4][8];       // [tile][row]

    const int tid = threadIdx.x;
    const int w   = tid >> 6;      // N-tile 0..3 (cols 16w..16w+15)
    const int l   = tid & 63;
    const int r   = l & 15;
    const int rl  = r & 7;         // real row within the 8-row group
    const int g   = l >> 4;
    const int rb  = blockIdx.x * 8;

    // zero-init hbuf once (uninitialized LDS read as A-frag could be NaN;
    // NaN * 0-weight would poison the accumulator)
    for (int i = tid; i < 2 * 8 * PITCH; i += 256) (&hbuf[0][0][0])[i] = 0.0f;

    // Loop-invariant weight frags for this wave's 16 cols: 6 short8 = 24 VGPR
    const int c = 16 * w + r;
    const bool cv = (c < HH);
    short8 Whi, Wlo, Uhi0, Ulo0, Uhi1, Ulo1;
    build_bfrag(W, 0, FF, c, cv, g, Whi, Wlo);
    build_bfrag(U, 0,  HH, c, cv, g, Uhi0, Ulo0);
    build_bfrag(U, 32, HH, c, cv, g, Uhi1, Ulo1);
    const float bias = cv ? b[c] : 0.0f;
    const float wd   = cv ? Wd[c] : 0.0f;
    __syncthreads();   // hbuf zero-init visible

    const float* xrow = x + (size_t)(rb + rl) * TT * FF + 8 * g;

    // nx = bias + x_t @ W (3 split products) — off the h path
    auto do_nx = [&](float4 a, float4 b2) -> f32x4 {
        short8 hi, lo;
        split8(a, b2, hi, lo);
        f32x4 t = {bias, bias, bias, bias};
        t = mfma16(hi, Whi, t);
        t = mfma16(lo, Whi, t);
        t = mfma16(hi, Wlo, t);
        return t;
    };

    // prologue: xacc for t=0; prefetch x_1 (pa), x_2 (pb)
    f32x4 xacc = do_nx(*(const float4*)(xrow), *(const float4*)(xrow + 4));
    float4 pa0 = *(const float4*)(xrow + FF),     pa1 = *(const float4*)(xrow + FF + 4);
    float4 pb0 = *(const float4*)(xrow + 2 * FF), pb1 = *(const float4*)(xrow + 2 * FF + 4);

    float hf[4];   // final h (C-layout) for the head

    auto step = [&](int t, bool first, float4& qa, float4& qb) {
        const int buf = t & 1, nbuf = buf ^ 1;
        // h_t reads first (deepest latency); rows clamped to the 8 real ones
        float4 h0a, h0b, h1a, h1b;
        if (!first) {
            const float* base = &hbuf[buf][rl][0];
            h0a = *(const float4*)(base + 8 * g);        // k 0..31 slice
            h0b = *(const float4*)(base + 8 * g + 4);
            h1a = *(const float4*)(base + 32 + 8 * g);   // k 32..49 slice (+0 pad)
            h1b = *(const float4*)(base + 32 + 8 * g + 4);
        }
        // x_{t+1}@W (independent of h)
        f32x4 nx = do_nx(qa, qb);
        int tn = t + 3; if (tn > TT - 1) tn = TT - 1;
        qa = *(const float4*)(xrow + (size_t)tn * FF);
        qb = *(const float4*)(xrow + (size_t)tn * FF + 4);

        f32x4 tot = xacc;
        if (!first) {
            short8 hh0, hl0, hh1, hl1;
            split8(h0a, h0b, hh0, hl0);
            split8(h1a, h1b, hh1, hl1);
            // two independent 3-chains, xacc as C-in of chain a
            f32x4 ca = mfma16(hh0, Uhi0, xacc);
            f32x4 cb = {0.0f, 0.0f, 0.0f, 0.0f};
            cb = mfma16(hh1, Uhi1, cb);
            ca = mfma16(hl0, Uhi0, ca);
            cb = mfma16(hl1, Uhi1, cb);
            ca = mfma16(hh0, Ulo0, ca);
            cb = mfma16(hh1, Ulo1, cb);
            tot = ca + cb;
        }

        // tanh + publish h_{t+1}: only rows 0..7 (g<2) are real
        float* wbase = &hbuf[nbuf][0][0];
#pragma unroll
        for (int i = 0; i < 4; ++i) {
            float h = fast_tanh(tot[i]);
            hf[i] = h;
            if (g < 2) wbase[(4 * g + i) * PITCH + 16 * w + r] = h;
        }
        xacc = nx;

        // LDS-only drain + raw barrier (x loads stay in flight)
        __builtin_amdgcn_sched_barrier(0);
        asm volatile("s_waitcnt lgkmcnt(0)");
        __builtin_amdgcn_sched_barrier(0);
        __builtin_amdgcn_s_barrier();
        __builtin_amdgcn_sched_barrier(0);
    };

    step(0, true, pa0, pa1);
    for (int t = 1; t < TT - 1; t += 2) {
        step(t,     false, pb0, pb1);
        step(t + 1, false, pa0, pa1);
    }
    step(TT - 1, false, pb0, pb1);

    // head: per-tile partial, combine across 4 tiles
#pragma unroll
    for (int i = 0; i < 4; ++i) {
        float p = hf[i] * wd;
        p += __shfl_xor(p, 1);
        p += __shfl_xor(p, 2);
        p += __shfl_xor(p, 4);
        p += __shfl_xor(p, 8);
        if (r == 0 && g < 2) headbuf[w][4 * g + i] = p;
    }
    __syncthreads();
    if (tid < 8)
        out[rb + tid] = fmaxf(headbuf[0][tid] + headbuf[1][tid] +
                              headbuf[2][tid] + headbuf[3][tid] + bd[0], 0.0f);
}

extern "C" void kernel_launch(void* const* d_in, const int* in_sizes, int n_in,
                              void* d_out, int out_size, void* d_ws, size_t ws_size,
                              hipStream_t stream) {
    const float* x  = (const float*)d_in[0];
    const float* W  = (const float*)d_in[1];
    const float* U  = (const float*)d_in[2];
    const float* b  = (const float*)d_in[3];
    const float* Wd = (const float*)d_in[4];
    const float* bd = (const float*)d_in[5];
    float* out = (float*)d_out;
    const int B = out_size;                       // 4096
    dim3 grid(B / 8), block(256);                 // 512 blocks, 4 waves, 8 rows
    hipLaunchKernelGGL(rnn_mfma, grid, block, 0, stream,
                       x, W, U, b, Wd, bd, out);
    (void)d_ws; (void)ws_size; (void)in_sizes; (void)n_in;
}

// Round 10
// 101.269 us; speedup vs baseline: 1.1269x; 1.1269x over previous
//
#include <hip/hip_runtime.h>

#define TT 200
#define FF 32
#define HH 50
#define HP 72   // fp16 pitch: 144B rows (16B-aligned for b128), banks spread 4-way max

typedef _Float16 half8 __attribute__((ext_vector_type(8)));   // 8 f16 = 4 VGPR
typedef __attribute__((ext_vector_type(4))) float f32x4;
typedef __attribute__((ext_vector_type(4))) unsigned int uint32x4;

// tanh(x) = 1 - 2/(exp2(2*log2e*x)+1): mul, exp2(T), add, rcp(T), fma
__device__ __forceinline__ float fast_tanh(float x) {
    float e = exp2f(2.885390082f * x);
    return fmaf(-2.0f, __builtin_amdgcn_rcpf(e + 1.0f), 1.0f);
}
__device__ __forceinline__ f32x4 mfmah(half8 a, half8 b, f32x4 c) {
    return __builtin_amdgcn_mfma_f32_16x16x32_f16(a, b, c, 0, 0, 0);
}

// fp16 B-frag of M[kdim x 50] col-slice (RNE). Layout as validated r4-r9:
// lane(r,g) elem e -> B[k=kbase+8g+e][col=c].
__device__ __forceinline__ half8 build_wfrag(const float* __restrict__ M, int kbase,
                                             int kmax, int c, bool cv, int g) {
    unsigned u[4];
#pragma unroll
    for (int q = 0; q < 4; ++q) {
        const int k0 = kbase + 8 * g + 2 * q, k1 = k0 + 1;
        _Float16 v0 = (_Float16)((cv && k0 < kmax) ? M[k0 * HH + c] : 0.0f);
        _Float16 v1 = (_Float16)((cv && k1 < kmax) ? M[k1 * HH + c] : 0.0f);
        u[q] = ((unsigned)__builtin_bit_cast(unsigned short, v1) << 16)
             |  __builtin_bit_cast(unsigned short, v0);
    }
    uint32x4 uu = {u[0], u[1], u[2], u[3]};
    return __builtin_bit_cast(half8, uu);
}

// 8 f32 -> half8 via v_cvt_pkrtz (4 instr; RTZ bias negligible on the x path)
__device__ __forceinline__ half8 cvt8(float4 a, float4 b) {
    unsigned u0 = __builtin_bit_cast(unsigned, __builtin_amdgcn_cvt_pkrtz(a.x, a.y));
    unsigned u1 = __builtin_bit_cast(unsigned, __builtin_amdgcn_cvt_pkrtz(a.z, a.w));
    unsigned u2 = __builtin_bit_cast(unsigned, __builtin_amdgcn_cvt_pkrtz(b.x, b.y));
    unsigned u3 = __builtin_bit_cast(unsigned, __builtin_amdgcn_cvt_pkrtz(b.z, b.w));
    uint32x4 uu = {u0, u1, u2, u3};
    return __builtin_bit_cast(half8, uu);
}

// r9 grid (512 blocks x 4 waves, 8 real rows M-duplicated, 2 phase-diverse
// blocks/CU) with the step body cut from ~245 to ~90 VALU instr/wave:
// single-product fp16 MFMA (3 MFMA/step, was 9), no split8 (was 72 VALU),
// h stored as fp16 (2 ds_read_b128, was 4), exp2-based tanh.
// r9 post-mortem: active-SIMD issue was 65% of wall -> issue-bound, so
// per-wave instruction count is the lever, not more TLP.
__global__
__attribute__((amdgpu_flat_work_group_size(256, 256)))
__attribute__((amdgpu_waves_per_eu(2)))
void rnn_fp16(const float* __restrict__ x, const float* __restrict__ W,
              const float* __restrict__ U, const float* __restrict__ b,
              const float* __restrict__ Wd, const float* __restrict__ bd,
              float* __restrict__ out)
{
    __shared__ _Float16 hb[2][8][HP];
    __shared__ float headbuf[4][8];

    const int tid = threadIdx.x;
    const int w   = tid >> 6;      // N-tile 0..3 (cols 16w..16w+15)
    const int l   = tid & 63;
    const int r   = l & 15;
    const int rl  = r & 7;         // real row in the 8-row group
    const int g   = l >> 4;
    const int rb  = blockIdx.x * 8;

    // zero-init hb once (pad cols 50..63 must read as 0; cols 64..71 unused)
    for (int i = tid; i < 2 * 8 * HP; i += 256) (&hb[0][0][0])[i] = (_Float16)0.0f;

    const int c = 16 * w + r;
    const bool cv = (c < HH);
    const half8 Wf = build_wfrag(W, 0,  FF, c, cv, g);
    const half8 U0 = build_wfrag(U, 0,  HH, c, cv, g);
    const half8 U1 = build_wfrag(U, 32, HH, c, cv, g);
    const float bias = cv ? b[c] : 0.0f;
    const float wd   = cv ? Wd[c] : 0.0f;
    __syncthreads();   // hb zero-init visible

    const float* xrow = x + (size_t)(rb + rl) * TT * FF + 8 * g;

    // nx = bias + x_t @ W  (1 MFMA; off the h-dependency path)
    auto do_nx = [&](float4 a, float4 b2) -> f32x4 {
        f32x4 t = {bias, bias, bias, bias};
        return mfmah(cvt8(a, b2), Wf, t);
    };

    // prologue: xacc for t=0; prefetch x_1 (pa), x_2 (pb)
    f32x4 xacc = do_nx(*(const float4*)(xrow), *(const float4*)(xrow + 4));
    float4 pa0 = *(const float4*)(xrow + FF),     pa1 = *(const float4*)(xrow + FF + 4);
    float4 pb0 = *(const float4*)(xrow + 2 * FF), pb1 = *(const float4*)(xrow + 2 * FF + 4);

    float hf[4];   // final h (C-layout) for the head

    auto step = [&](int t, bool first, float4& qa, float4& qb) {
        const int buf = t & 1, nbuf = buf ^ 1;
        // h_t fp16 reads first (deepest latency on the path)
        half8 h0, h1;
        if (!first) {
            h0 = *(const half8*)(&hb[buf][rl][8 * g]);        // k 0..31
            h1 = *(const half8*)(&hb[buf][rl][32 + 8 * g]);   // k 32..63 (pad 0)
        }
        // x_{t+1}@W (independent of h), then advance the prefetch
        f32x4 nx = do_nx(qa, qb);
        int tn = t + 3; if (tn > TT - 1) tn = TT - 1;
        qa = *(const float4*)(xrow + (size_t)tn * FF);
        qb = *(const float4*)(xrow + (size_t)tn * FF + 4);

        f32x4 tot = xacc;
        if (!first) {
            tot = mfmah(h0, U0, tot);   // C-chained MFMAs run at throughput
            tot = mfmah(h1, U1, tot);   // rate (m119), so chaining is fine
        }

        // tanh + fp16 publish (rows 0..7 only; dup rows 8..15 identical)
#pragma unroll
        for (int i = 0; i < 4; ++i) {
            float h = fast_tanh(tot[i]);
            hf[i] = h;
            if (g < 2) hb[nbuf][4 * g + i][16 * w + r] = (_Float16)h;
        }
        xacc = nx;

        // LDS-only drain + raw barrier (x global loads stay in flight)
        __builtin_amdgcn_sched_barrier(0);
        asm volatile("s_waitcnt lgkmcnt(0)");
        __builtin_amdgcn_sched_barrier(0);
        __builtin_amdgcn_s_barrier();
        __builtin_amdgcn_sched_barrier(0);
    };

    step(0, true, pa0, pa1);
    for (int t = 1; t < TT - 1; t += 2) {
        step(t,     false, pb0, pb1);
        step(t + 1, false, pa0, pa1);
    }
    step(TT - 1, false, pb0, pb1);

    // head: per-tile partial, combine across 4 tiles
#pragma unroll
    for (int i = 0; i < 4; ++i) {
        float p = hf[i] * wd;
        p += __shfl_xor(p, 1);
        p += __shfl_xor(p, 2);
        p += __shfl_xor(p, 4);
        p += __shfl_xor(p, 8);
        if (r == 0 && g < 2) headbuf[w][4 * g + i] = p;
    }
    __syncthreads();
    if (tid < 8)
        out[rb + tid] = fmaxf(headbuf[0][tid] + headbuf[1][tid] +
                              headbuf[2][tid] + headbuf[3][tid] + bd[0], 0.0f);
}

extern "C" void kernel_launch(void* const* d_in, const int* in_sizes, int n_in,
                              void* d_out, int out_size, void* d_ws, size_t ws_size,
                              hipStream_t stream) {
    const float* x  = (const float*)d_in[0];
    const float* W  = (const float*)d_in[1];
    const float* U  = (const float*)d_in[2];
    const float* b  = (const float*)d_in[3];
    const float* Wd = (const float*)d_in[4];
    const float* bd = (const float*)d_in[5];
    float* out = (float*)d_out;
    const int B = out_size;                       // 4096
    dim3 grid(B / 8), block(256);                 // 512 blocks, 4 waves, 8 rows
    hipLaunchKernelGGL(rnn_fp16, grid, block, 0, stream,
                       x, W, U, b, Wd, bd, out);
    (void)d_ws; (void)ws_size; (void)in_sizes; (void)n_in;
}

// Round 11
// 84.262 us; speedup vs baseline: 1.3543x; 1.2018x over previous
//
#include <hip/hip_runtime.h>

#define TT 200
#define FF 32
#define HH 50
#define HP 80   // f16 pitch: 160B row stride -> <=2-way read banks (free)

typedef _Float16 half8 __attribute__((ext_vector_type(8)));   // 8 f16 = 4 VGPR
typedef __attribute__((ext_vector_type(4))) float f32x4;
typedef __attribute__((ext_vector_type(4))) unsigned int uint32x4;

// tanh(x) = 1 - 2/(exp2(2*log2e*x)+1)
__device__ __forceinline__ float fast_tanh(float x) {
    float e = exp2f(2.885390082f * x);
    return fmaf(-2.0f, __builtin_amdgcn_rcpf(e + 1.0f), 1.0f);
}
__device__ __forceinline__ f32x4 mfmah(half8 a, half8 b, f32x4 c) {
    return __builtin_amdgcn_mfma_f32_16x16x32_f16(a, b, c, 0, 0, 0);
}

// fp16 B-frag of M[kdim x 50] col-slice (RNE). Layout (validated r4-r10):
// lane(r,g) elem e -> B[k=kbase+8g+e][col=c].
__device__ __forceinline__ half8 build_wfrag(const float* __restrict__ M, int kbase,
                                             int kmax, int c, bool cv, int g) {
    unsigned u[4];
#pragma unroll
    for (int q = 0; q < 4; ++q) {
        const int k0 = kbase + 8 * g + 2 * q, k1 = k0 + 1;
        _Float16 v0 = (_Float16)((cv && k0 < kmax) ? M[k0 * HH + c] : 0.0f);
        _Float16 v1 = (_Float16)((cv && k1 < kmax) ? M[k1 * HH + c] : 0.0f);
        u[q] = ((unsigned)__builtin_bit_cast(unsigned short, v1) << 16)
             |  __builtin_bit_cast(unsigned short, v0);
    }
    uint32x4 uu = {u[0], u[1], u[2], u[3]};
    return __builtin_bit_cast(half8, uu);
}

// 8 f32 -> half8 via v_cvt_pkrtz (x path only; h stores stay RNE)
__device__ __forceinline__ half8 cvt8(float4 a, float4 b) {
    unsigned u0 = __builtin_bit_cast(unsigned, __builtin_amdgcn_cvt_pkrtz(a.x, a.y));
    unsigned u1 = __builtin_bit_cast(unsigned, __builtin_amdgcn_cvt_pkrtz(a.z, a.w));
    unsigned u2 = __builtin_bit_cast(unsigned, __builtin_amdgcn_cvt_pkrtz(b.x, b.y));
    unsigned u3 = __builtin_bit_cast(unsigned, __builtin_amdgcn_cvt_pkrtz(b.z, b.w));
    uint32x4 uu = {u0, u1, u2, u3};
    return __builtin_bit_cast(half8, uu);
}

// ONE WAVE per block, 4 real batch rows (M-duplicated x4 to fill the 16-row
// MFMA), all 50 cols (4 N-tiles). Everything wave-private: DS ops of one
// wave execute in order (r7-validated), so NO barrier and NO waitcnt are on
// the step path. M-dup exploit: lane (r,g) holds tile g's real rows 0..3 in
// its own C regs, so each lane tanh's/stores ONLY tile g -> 4 tanh + 4
// conflict-free ds_write_b16 per step (was 16+16). 1024 blocks = 4 phase-
// independent chains/CU (r10 post-mortem: path ~1300 cyc >> issue ~650;
// barrier + LDS roundtrip + chain latency is the target).
__global__
__attribute__((amdgpu_flat_work_group_size(64, 64)))
__attribute__((amdgpu_waves_per_eu(1, 1)))
void rnn_fp16(const float* __restrict__ x, const float* __restrict__ W,
              const float* __restrict__ U, const float* __restrict__ b,
              const float* __restrict__ Wd, const float* __restrict__ bd,
              float* __restrict__ out)
{
    __shared__ _Float16 hb[2][4][HP];   // [buf][real row][col]; no init needed

    const int l  = threadIdx.x & 63;
    const int r  = l & 15;
    const int g  = l >> 4;
    const int rl = r & 3;          // real row (M rows duplicated x4)
    const int rb = blockIdx.x * 4;

    // weight frags for all 4 N-tiles: 12 half8 = 48 VGPR
    half8 Wf[4], U0[4], U1[4];
    float bias[4];
#pragma unroll
    for (int n = 0; n < 4; ++n) {
        const int c = 16 * n + r;
        const bool cv = (c < HH);
        Wf[n] = build_wfrag(W, 0,  FF, c, cv, g);
        U0[n] = build_wfrag(U, 0,  HH, c, cv, g);
        U1[n] = build_wfrag(U, 32, HH, c, cv, g);
        bias[n] = cv ? b[c] : 0.0f;
    }
    const int cg = 16 * g + r;                      // this lane's head col
    const float wd = (cg < HH) ? Wd[cg] : 0.0f;

    const float* xrow = x + (size_t)(rb + rl) * TT * FF + 8 * g;

    // nx[n] = bias + x_t @ W (1 MFMA per tile; off the h path)
    auto do_nx = [&](float4 a, float4 b2, f32x4 (&nx)[4]) {
        half8 xa = cvt8(a, b2);
#pragma unroll
        for (int n = 0; n < 4; ++n) {
            f32x4 t = {bias[n], bias[n], bias[n], bias[n]};
            nx[n] = mfmah(xa, Wf[n], t);
        }
    };

    // prologue: xacc for t=0; prefetch x_1 (pa), x_2 (pb)
    f32x4 xacc[4];
    do_nx(*(const float4*)(xrow), *(const float4*)(xrow + 4), xacc);
    float4 pa0 = *(const float4*)(xrow + FF),     pa1 = *(const float4*)(xrow + FF + 4);
    float4 pb0 = *(const float4*)(xrow + 2 * FF), pb1 = *(const float4*)(xrow + 2 * FF + 4);

    float hf[4];   // tanh of tile g, real rows 0..3 (this lane's share)

    auto step = [&](int t, bool first, float4& qa, float4& qb) {
        const int buf = t & 1, nbuf = buf ^ 1;
        // h_t reads first (deepest latency); in-order DS makes them safe
        half8 h0, h1;
        if (!first) {
            h0 = *(const half8*)(&hb[buf][rl][8 * g]);        // k 0..31
            h1 = *(const half8*)(&hb[buf][rl][32 + 8 * g]);   // k 32..63 (pad 0)
        }
        // x_{t+1}@W (independent of h) + advance prefetch to x_{t+3}
        f32x4 nx[4];
        do_nx(qa, qb, nx);
        int tn = t + 3; if (tn > TT - 1) tn = TT - 1;
        qa = *(const float4*)(xrow + (size_t)tn * FF);
        qb = *(const float4*)(xrow + (size_t)tn * FF + 4);

        f32x4 tot[4];
        if (!first) {
#pragma unroll
            for (int n = 0; n < 4; ++n) {     // 2 independent 1-dep chains
                f32x4 ca = mfmah(h0, U0[n], xacc[n]);
                f32x4 cb = {0.0f, 0.0f, 0.0f, 0.0f};
                cb = mfmah(h1, U1[n], cb);
                tot[n] = ca + cb;
            }
        } else {
#pragma unroll
            for (int n = 0; n < 4; ++n) tot[n] = xacc[n];
        }

        // M-dup exploit: this lane processes only tile g (rows 4g+i == real i)
        f32x4 t01 = (g & 1) ? tot[1] : tot[0];
        f32x4 t23 = (g & 1) ? tot[3] : tot[2];
        f32x4 myt = (g & 2) ? t23 : t01;
#pragma unroll
        for (int i = 0; i < 4; ++i) {
            hf[i] = fast_tanh(myt[i]);
            hb[nbuf][i][16 * g + r] = (_Float16)hf[i];   // 64 lanes, 2/bank: free
        }
#pragma unroll
        for (int n = 0; n < 4; ++n) xacc[n] = nx[n];
        // NO barrier, NO waitcnt: wave-private, in-order DS
    };

    step(0, true, pa0, pa1);
    for (int t = 1; t < TT - 1; t += 2) {
        step(t,     false, pb0, pb1);
        step(t + 1, false, pa0, pa1);
    }
    step(TT - 1, false, pb0, pb1);

    // head: out[row i] = relu(sum_c h[i][c]*Wd[c] + bd); each lane holds
    // col cg for rows 0..3 -> full 64-lane butterfly gives every lane the sum
    float p[4];
#pragma unroll
    for (int i = 0; i < 4; ++i) {
        float v = hf[i] * wd;
#pragma unroll
        for (int m = 1; m <= 32; m <<= 1) v += __shfl_xor(v, m);
        p[i] = v;
    }
    if (l == 0) {
        const float bdv = bd[0];
        out[rb + 0] = fmaxf(p[0] + bdv, 0.0f);
        out[rb + 1] = fmaxf(p[1] + bdv, 0.0f);
        out[rb + 2] = fmaxf(p[2] + bdv, 0.0f);
        out[rb + 3] = fmaxf(p[3] + bdv, 0.0f);
    }
}

extern "C" void kernel_launch(void* const* d_in, const int* in_sizes, int n_in,
                              void* d_out, int out_size, void* d_ws, size_t ws_size,
                              hipStream_t stream) {
    const float* x  = (const float*)d_in[0];
    const float* W  = (const float*)d_in[1];
    const float* U  = (const float*)d_in[2];
    const float* b  = (const float*)d_in[3];
    const float* Wd = (const float*)d_in[4];
    const float* bd = (const float*)d_in[5];
    float* out = (float*)d_out;
    const int B = out_size;                       // 4096
    dim3 grid(B / 4), block(64);                  // 1024 blocks, 1 wave, 4 rows
    hipLaunchKernelGGL(rnn_fp16, grid, block, 0, stream,
                       x, W, U, b, Wd, bd, out);
    (void)d_ws; (void)ws_size; (void)in_sizes; (void)n_in;
}

// Round 12
// 78.902 us; speedup vs baseline: 1.4463x; 1.0679x over previous
//
#include <hip/hip_runtime.h>

#define TT 200
#define FF 32
#define HH 50
#define HP 80   // f16 pitch: read bcast 8 distinct 16B addrs, write 2-way: free

typedef _Float16 half8 __attribute__((ext_vector_type(8)));   // 8 f16 = 4 VGPR
typedef __attribute__((ext_vector_type(4))) float f32x4;
typedef __attribute__((ext_vector_type(4))) unsigned int uint32x4;

// tanh(x) = 1 - 2/(exp2(2*log2e*x)+1)
__device__ __forceinline__ float fast_tanh(float x) {
    float e = exp2f(2.885390082f * x);
    return fmaf(-2.0f, __builtin_amdgcn_rcpf(e + 1.0f), 1.0f);
}
__device__ __forceinline__ f32x4 mfmah(half8 a, half8 b, f32x4 c) {
    return __builtin_amdgcn_mfma_f32_16x16x32_f16(a, b, c, 0, 0, 0);
}

// fp16 B-frag of M[kdim x 50] col-slice (RNE). Layout (validated r4-r11):
// lane(r,g) elem e -> B[k=kbase+8g+e][col=c].
__device__ __forceinline__ half8 build_wfrag(const float* __restrict__ M, int kbase,
                                             int kmax, int c, bool cv, int g) {
    unsigned u[4];
#pragma unroll
    for (int q = 0; q < 4; ++q) {
        const int k0 = kbase + 8 * g + 2 * q, k1 = k0 + 1;
        _Float16 v0 = (_Float16)((cv && k0 < kmax) ? M[k0 * HH + c] : 0.0f);
        _Float16 v1 = (_Float16)((cv && k1 < kmax) ? M[k1 * HH + c] : 0.0f);
        u[q] = ((unsigned)__builtin_bit_cast(unsigned short, v1) << 16)
             |  __builtin_bit_cast(unsigned short, v0);
    }
    uint32x4 uu = {u[0], u[1], u[2], u[3]};
    return __builtin_bit_cast(half8, uu);
}

// 8 f32 -> half8 via v_cvt_pkrtz (x path only)
__device__ __forceinline__ half8 cvt8(float4 a, float4 b) {
    unsigned u0 = __builtin_bit_cast(unsigned, __builtin_amdgcn_cvt_pkrtz(a.x, a.y));
    unsigned u1 = __builtin_bit_cast(unsigned, __builtin_amdgcn_cvt_pkrtz(a.z, a.w));
    unsigned u2 = __builtin_bit_cast(unsigned, __builtin_amdgcn_cvt_pkrtz(b.x, b.y));
    unsigned u3 = __builtin_bit_cast(unsigned, __builtin_amdgcn_cvt_pkrtz(b.z, b.w));
    uint32x4 uu = {u0, u1, u2, u3};
    return __builtin_bit_cast(half8, uu);
}

// ONE WAVE per block, 2 real rows (M-dup x8), all 50 cols. Barrier-free
// wave-private recurrence (r7/r11-validated in-order DS). 2048 blocks ->
// TWO phase-independent waves per SIMD fill each other's stalls (no
// barrier = no phase lock, unlike r9). VALU slimmed (r11 post-mortem:
// ~480 cyc/wave-step, half of it self-inflicted data movement):
//  - biasv[] as persistent MFMA C-source (kills 16 bias movs/step)
//  - serial 2-MFMA chain per tile (kills 16 zero-movs + 16 adds)
//  - xacc ping-pong via two named arrays by reference (kills 16 movs)
//  - 2 rows -> 2 tanh + 6 cndmask + 2 cvt + 2 ds_write (was 4/12/4/4)
__global__
__attribute__((amdgpu_flat_work_group_size(64, 64)))
__attribute__((amdgpu_waves_per_eu(2)))
void rnn_fp16(const float* __restrict__ x, const float* __restrict__ W,
              const float* __restrict__ U, const float* __restrict__ b,
              const float* __restrict__ Wd, const float* __restrict__ bd,
              float* __restrict__ out)
{
    __shared__ _Float16 hb[2][2][HP];   // [buf][real row][col]

    const int l  = threadIdx.x & 63;
    const int r  = l & 15;
    const int g  = l >> 4;
    const int rl = r & 1;          // real row (M rows duplicated x8)
    const int rb = blockIdx.x * 2;
    const bool gs1 = (g & 1) != 0, gs2 = (g & 2) != 0;

    // weight frags (12 half8 = 48 VGPR) + persistent bias C-source (16 VGPR)
    half8 Wf[4], U0[4], U1[4];
    f32x4 biasv[4];
#pragma unroll
    for (int n = 0; n < 4; ++n) {
        const int c = 16 * n + r;
        const bool cv = (c < HH);
        Wf[n] = build_wfrag(W, 0,  FF, c, cv, g);
        U0[n] = build_wfrag(U, 0,  HH, c, cv, g);
        U1[n] = build_wfrag(U, 32, HH, c, cv, g);
        const float bv = cv ? b[c] : 0.0f;
        biasv[n] = (f32x4){bv, bv, bv, bv};
    }
    const int cg = 16 * g + r;                      // this lane's head col
    const float wd = (cg < HH) ? Wd[cg] : 0.0f;

    const float* xrow = x + (size_t)(rb + rl) * TT * FF + 8 * g;

    // nx[n] = biasv + x_t @ W (1 MFMA/tile, C = persistent biasv regs)
    auto do_nx = [&](float4 a, float4 b2, f32x4 (&nx)[4]) {
        half8 xa = cvt8(a, b2);
#pragma unroll
        for (int n = 0; n < 4; ++n) nx[n] = mfmah(xa, Wf[n], biasv[n]);
    };

    // prologue: xc = x_0@W; prefetch x_1 (pa), x_2 (pb)
    f32x4 xc[4], xn[4];
    do_nx(*(const float4*)(xrow), *(const float4*)(xrow + 4), xc);
    float4 pa0 = *(const float4*)(xrow + FF),     pa1 = *(const float4*)(xrow + FF + 4);
    float4 pb0 = *(const float4*)(xrow + 2 * FF), pb1 = *(const float4*)(xrow + 2 * FF + 4);

    float hf0 = 0.0f, hf1 = 0.0f;   // this lane's final h (col cg, rows 0/1)

    // step t: reads hb[buf=t&1] (skip if first), writes hb[buf^1].
    // xcur = bias + x_t@W (from prev step); xnext computed here.
    auto step = [&](int t, bool first, int buf,
                    f32x4 (&xcur)[4], f32x4 (&xnext)[4], float4& qa, float4& qb) {
        half8 h0, h1;
        if (!first) {
            h0 = *(const half8*)(&hb[buf][rl][8 * g]);        // k 0..31
            h1 = *(const half8*)(&hb[buf][rl][32 + 8 * g]);   // k 32..63 (pad 0)
        }
        // x_{t+1}@W (independent of h) + advance prefetch to x_{t+3}
        do_nx(qa, qb, xnext);
        int tn = t + 3; if (tn > TT - 1) tn = TT - 1;
        qa = *(const float4*)(xrow + (size_t)tn * FF);
        qb = *(const float4*)(xrow + (size_t)tn * FF + 4);

        f32x4 tot[4];
        if (!first) {
#pragma unroll
            for (int n = 0; n < 4; ++n)   // 4 indep serial 2-chains, no adds
                tot[n] = mfmah(h1, U1[n], mfmah(h0, U0[n], xcur[n]));
        } else {
#pragma unroll
            for (int n = 0; n < 4; ++n) tot[n] = xcur[n];
        }

        // M-dup select: lane owns tile g; only C rows i=0,1 are real rows
        float a0 = gs1 ? tot[1][0] : tot[0][0];
        float a1 = gs1 ? tot[1][1] : tot[0][1];
        float c0 = gs1 ? tot[3][0] : tot[2][0];
        float c1 = gs1 ? tot[3][1] : tot[2][1];
        float m0 = gs2 ? c0 : a0;
        float m1 = gs2 ? c1 : a1;
        hf0 = fast_tanh(m0);
        hf1 = fast_tanh(m1);
        hb[buf ^ 1][0][cg] = (_Float16)hf0;   // 2-way write banks: free
        hb[buf ^ 1][1][cg] = (_Float16)hf1;
        // NO barrier, NO waitcnt: wave-private, in-order DS pipe
    };

    step(0, true, 0, xc, xn, pa0, pa1);
    for (int t = 1; t < TT - 1; t += 2) {
        step(t,     false, 1, xn, xc, pb0, pb1);
        step(t + 1, false, 0, xc, xn, pa0, pa1);
    }
    step(TT - 1, false, 1, xn, xc, pb0, pb1);   // TT even -> last t odd, buf=1

    // head: out[row i] = relu(sum_c h[i][c]*Wd[c] + bd)
    float p0 = hf0 * wd, p1 = hf1 * wd;
#pragma unroll
    for (int m = 1; m <= 32; m <<= 1) {
        p0 += __shfl_xor(p0, m);
        p1 += __shfl_xor(p1, m);
    }
    if (l == 0) {
        const float bdv = bd[0];
        out[rb + 0] = fmaxf(p0 + bdv, 0.0f);
        out[rb + 1] = fmaxf(p1 + bdv, 0.0f);
    }
}

extern "C" void kernel_launch(void* const* d_in, const int* in_sizes, int n_in,
                              void* d_out, int out_size, void* d_ws, size_t ws_size,
                              hipStream_t stream) {
    const float* x  = (const float*)d_in[0];
    const float* W  = (const float*)d_in[1];
    const float* U  = (const float*)d_in[2];
    const float* b  = (const float*)d_in[3];
    const float* Wd = (const float*)d_in[4];
    const float* bd = (const float*)d_in[5];
    float* out = (float*)d_out;
    const int B = out_size;                       // 4096
    dim3 grid(B / 2), block(64);                  // 2048 blocks, 1 wave, 2 rows
    hipLaunchKernelGGL(rnn_fp16, grid, block, 0, stream,
                       x, W, U, b, Wd, bd, out);
    (void)d_ws; (void)ws_size; (void)in_sizes; (void)n_in;
}

// Round 13
// 77.529 us; speedup vs baseline: 1.4720x; 1.0177x over previous
//
#include <hip/hip_runtime.h>

#define TT 200
#define FF 32
#define HH 50
#define HP 80   // f16 pitch: read bcast 8 distinct 16B addrs, write 2-way: free

typedef _Float16 half8 __attribute__((ext_vector_type(8)));   // 8 f16 = 4 VGPR
typedef __attribute__((ext_vector_type(4))) float f32x4;
typedef __attribute__((ext_vector_type(4))) unsigned int uint32x4;

// tanh(x) = 1 - 2/(exp2(2*log2e*x)+1)
__device__ __forceinline__ float fast_tanh(float x) {
    float e = exp2f(2.885390082f * x);
    return fmaf(-2.0f, __builtin_amdgcn_rcpf(e + 1.0f), 1.0f);
}
__device__ __forceinline__ f32x4 mfmah(half8 a, half8 b, f32x4 c) {
    return __builtin_amdgcn_mfma_f32_16x16x32_f16(a, b, c, 0, 0, 0);
}

// fp16 B-frag of M[kdim x 50] col-slice (RNE). Layout (validated r4-r12):
// lane(r,g) elem e -> B[k=kbase+8g+e][col=c].
__device__ __forceinline__ half8 build_wfrag(const float* __restrict__ M, int kbase,
                                             int kmax, int c, bool cv, int g) {
    unsigned u[4];
#pragma unroll
    for (int q = 0; q < 4; ++q) {
        const int k0 = kbase + 8 * g + 2 * q, k1 = k0 + 1;
        _Float16 v0 = (_Float16)((cv && k0 < kmax) ? M[k0 * HH + c] : 0.0f);
        _Float16 v1 = (_Float16)((cv && k1 < kmax) ? M[k1 * HH + c] : 0.0f);
        u[q] = ((unsigned)__builtin_bit_cast(unsigned short, v1) << 16)
             |  __builtin_bit_cast(unsigned short, v0);
    }
    uint32x4 uu = {u[0], u[1], u[2], u[3]};
    return __builtin_bit_cast(half8, uu);
}

// 8 f32 -> half8 via v_cvt_pkrtz (x path only)
__device__ __forceinline__ half8 cvt8(float4 a, float4 b) {
    unsigned u0 = __builtin_bit_cast(unsigned, __builtin_amdgcn_cvt_pkrtz(a.x, a.y));
    unsigned u1 = __builtin_bit_cast(unsigned, __builtin_amdgcn_cvt_pkrtz(a.z, a.w));
    unsigned u2 = __builtin_bit_cast(unsigned, __builtin_amdgcn_cvt_pkrtz(b.x, b.y));
    unsigned u3 = __builtin_bit_cast(unsigned, __builtin_amdgcn_cvt_pkrtz(b.z, b.w));
    uint32x4 uu = {u0, u1, u2, u3};
    return __builtin_bit_cast(half8, uu);
}

// r12 structure (1 wave/block, 2 real rows M-dup x8, barrier-free wave-
// private LDS recurrence, 2048 blocks = 2 phase-independent waves/SIMD)
// with the AGPR-shuttle fix:
//  - waves_per_eu(2,2): EXACTLY 2 waves/EU -> 256-VGPR budget. r12's
//    waves_per_eu(2) (min only) let the allocator squeeze to 64 VGPR,
//    parking MFMA state in AGPRs; VALU can't read AGPRs, so every
//    tot/select/tanh consumption paid v_accvgpr_read (~35 hidden
//    VALU/step = the gap between 73 measured and ~40 static instrs).
//  - persistent zerov[] C-source -> the two h-MFMA chains run in
//    PARALLEL (path -1 dependent MFMA) with no per-step zero-init.
__global__
__attribute__((amdgpu_flat_work_group_size(64, 64)))
__attribute__((amdgpu_waves_per_eu(2, 2)))
void rnn_fp16(const float* __restrict__ x, const float* __restrict__ W,
              const float* __restrict__ U, const float* __restrict__ b,
              const float* __restrict__ Wd, const float* __restrict__ bd,
              float* __restrict__ out)
{
    __shared__ _Float16 hb[2][2][HP];   // [buf][real row][col]

    const int l  = threadIdx.x & 63;
    const int r  = l & 15;
    const int g  = l >> 4;
    const int rl = r & 1;          // real row (M rows duplicated x8)
    const int rb = blockIdx.x * 2;
    const bool gs1 = (g & 1) != 0, gs2 = (g & 2) != 0;

    // weight frags (48 VGPR) + persistent bias / zero C-sources (32 VGPR)
    half8 Wf[4], U0[4], U1[4];
    f32x4 biasv[4], zerov[4];
#pragma unroll
    for (int n = 0; n < 4; ++n) {
        const int c = 16 * n + r;
        const bool cv = (c < HH);
        Wf[n] = build_wfrag(W, 0,  FF, c, cv, g);
        U0[n] = build_wfrag(U, 0,  HH, c, cv, g);
        U1[n] = build_wfrag(U, 32, HH, c, cv, g);
        const float bv = cv ? b[c] : 0.0f;
        biasv[n] = (f32x4){bv, bv, bv, bv};
        zerov[n] = (f32x4){0.0f, 0.0f, 0.0f, 0.0f};
    }
    const int cg = 16 * g + r;                      // this lane's head col
    const float wd = (cg < HH) ? Wd[cg] : 0.0f;

    const float* xrow = x + (size_t)(rb + rl) * TT * FF + 8 * g;

    // nx[n] = biasv + x_t @ W (1 MFMA/tile, C = persistent biasv regs)
    auto do_nx = [&](float4 a, float4 b2, f32x4 (&nx)[4]) {
        half8 xa = cvt8(a, b2);
#pragma unroll
        for (int n = 0; n < 4; ++n) nx[n] = mfmah(xa, Wf[n], biasv[n]);
    };

    // prologue: xc = x_0@W; prefetch x_1 (pa), x_2 (pb)
    f32x4 xc[4], xn[4];
    do_nx(*(const float4*)(xrow), *(const float4*)(xrow + 4), xc);
    float4 pa0 = *(const float4*)(xrow + FF),     pa1 = *(const float4*)(xrow + FF + 4);
    float4 pb0 = *(const float4*)(xrow + 2 * FF), pb1 = *(const float4*)(xrow + 2 * FF + 4);

    float hf0 = 0.0f, hf1 = 0.0f;   // this lane's final h (col cg, rows 0/1)

    // step t: reads hb[buf=t&1] (skip if first), writes hb[buf^1].
    auto step = [&](int t, bool first, int buf,
                    f32x4 (&xcur)[4], f32x4 (&xnext)[4], float4& qa, float4& qb) {
        half8 h0, h1;
        if (!first) {
            h0 = *(const half8*)(&hb[buf][rl][8 * g]);        // k 0..31
            h1 = *(const half8*)(&hb[buf][rl][32 + 8 * g]);   // k 32..63 (pad 0)
        }
        // x_{t+1}@W (independent of h) + advance prefetch to x_{t+3}
        do_nx(qa, qb, xnext);
        int tn = t + 3; if (tn > TT - 1) tn = TT - 1;
        qa = *(const float4*)(xrow + (size_t)tn * FF);
        qb = *(const float4*)(xrow + (size_t)tn * FF + 4);

        f32x4 tot[4];
        if (!first) {
#pragma unroll
            for (int n = 0; n < 4; ++n) {   // two PARALLEL 1-dep chains + add
                f32x4 ca = mfmah(h0, U0[n], xcur[n]);
                f32x4 cb = mfmah(h1, U1[n], zerov[n]);
                tot[n] = ca + cb;
            }
        } else {
#pragma unroll
            for (int n = 0; n < 4; ++n) tot[n] = xcur[n];
        }

        // M-dup select: lane owns tile g; C rows i=0,1 are the real rows
        float a0 = gs1 ? tot[1][0] : tot[0][0];
        float a1 = gs1 ? tot[1][1] : tot[0][1];
        float c0 = gs1 ? tot[3][0] : tot[2][0];
        float c1 = gs1 ? tot[3][1] : tot[2][1];
        float m0 = gs2 ? c0 : a0;
        float m1 = gs2 ? c1 : a1;
        hf0 = fast_tanh(m0);
        hf1 = fast_tanh(m1);
        hb[buf ^ 1][0][cg] = (_Float16)hf0;   // 2-way write banks: free
        hb[buf ^ 1][1][cg] = (_Float16)hf1;
        // NO barrier, NO waitcnt: wave-private, in-order DS pipe
    };

    step(0, true, 0, xc, xn, pa0, pa1);
    for (int t = 1; t < TT - 1; t += 2) {
        step(t,     false, 1, xn, xc, pb0, pb1);
        step(t + 1, false, 0, xc, xn, pa0, pa1);
    }
    step(TT - 1, false, 1, xn, xc, pb0, pb1);   // TT even -> last t odd, buf=1

    // head: out[row i] = relu(sum_c h[i][c]*Wd[c] + bd)
    float p0 = hf0 * wd, p1 = hf1 * wd;
#pragma unroll
    for (int m = 1; m <= 32; m <<= 1) {
        p0 += __shfl_xor(p0, m);
        p1 += __shfl_xor(p1, m);
    }
    if (l == 0) {
        const float bdv = bd[0];
        out[rb + 0] = fmaxf(p0 + bdv, 0.0f);
        out[rb + 1] = fmaxf(p1 + bdv, 0.0f);
    }
}

extern "C" void kernel_launch(void* const* d_in, const int* in_sizes, int n_in,
                              void* d_out, int out_size, void* d_ws, size_t ws_size,
                              hipStream_t stream) {
    const float* x  = (const float*)d_in[0];
    const float* W  = (const float*)d_in[1];
    const float* U  = (const float*)d_in[2];
    const float* b  = (const float*)d_in[3];
    const float* Wd = (const float*)d_in[4];
    const float* bd = (const float*)d_in[5];
    float* out = (float*)d_out;
    const int B = out_size;                       // 4096
    dim3 grid(B / 2), block(64);                  // 2048 blocks, 1 wave, 2 rows
    hipLaunchKernelGGL(rnn_fp16, grid, block, 0, stream,
                       x, W, U, b, Wd, bd, out);
    (void)d_ws; (void)ws_size; (void)in_sizes; (void)n_in;
}